// Round 7
// baseline (126.831 us; speedup 1.0000x reference)
//
#include <hip/hip_runtime.h>
#include <cstdint>
#include <cstddef>

// Problem constants (match reference file)
#define BB 4
#define MM 8192
#define NN 6890
#define NSEG 128
#define SEGN 54           // ceil(6890/128); last segment has 32
#define CHUNKS 2          // MM / MQ
#define MQ 4096           // queries per nn block
#define QT 16             // queries per thread
#define NPAIR 8           // QT/2 packed-f32 pairs
#define TPB 256
#define NQ (BB * MM)      // 32768 queries
#define FBLK 128          // finalize blocks (x256 threads = NQ)

typedef float v2f __attribute__((ext_vector_type(2)));

static constexpr float MIN_T2 = 0.005f * 0.005f;   // MIN_DIST_THRESH^2

// ws layout (bytes):
//   [0, 16777216)            f32 partials[NSEG][NQ]  (min of e over segment,
//                            filtered set; e = s2 - 2 c.s, shifted by -qc2)
//   [16777216, 16777728)     float bsum[128]
//   [16777728, 16778240)     int   bmatch[128]
//   [16778240, 16778244)     uint  counter (zeroed by nn block 0)
#define OFF_BSUM   16777216
#define OFF_BMATCH 16777728
#define OFF_CNT    16778240

// Kernel 1: per-(batch, m-chunk, n-segment) NN, MIN-VALUE ONLY (no index
// tracking in the hot loop: cmp+2 cndmask per query -> 1 v_min, cutting VALU
// cycles 96->64 per candidate-thread; the argmin index is reconstructed
// bit-exactly in finalize by rescanning the winning segment).
// NO hot-path atomics (R3), NO grid.sync (R4): plain coalesced f32 stores.
__global__ __launch_bounds__(TPB, 4) void nn_kernel(
    const float* __restrict__ cloth, const float* __restrict__ vt,
    const int* __restrict__ valid, float* __restrict__ partials,
    unsigned int* __restrict__ counter)
{
    __shared__ float4 lds[SEGN];
    int bid   = blockIdx.x;            // 1024 blocks = 4/CU
    if (bid == 0 && threadIdx.x == 0) *counter = 0;  // for finalize last-block
    int seg   = bid & (NSEG - 1);
    int chunk = (bid >> 7) & (CHUNKS - 1);
    int b     = bid >> 8;
    int n0    = seg * SEGN;
    int segn  = (NN - n0 < SEGN) ? (NN - n0) : SEGN;

    // fused candidate prep: (-2x,-2y,-2z, s2 or +inf if invalid)
    if (threadIdx.x < segn) {
        int n = n0 + threadIdx.x;
        const float* p = vt + ((size_t)b * NN + n) * 3;
        float x = p[0], y = p[1], z = p[2];
        float s2 = x * x + y * y + z * z;
        if (valid[b * NN + n] <= 0) s2 = __builtin_inff();
        lds[threadIdx.x] = make_float4(-2.0f * x, -2.0f * y, -2.0f * z, s2);
    }

    v2f qx[NPAIR], qy[NPAIR], qz[NPAIR], bd[NPAIR];
    float tmin[QT];
    int m0 = chunk * MQ + threadIdx.x;
#pragma unroll
    for (int j = 0; j < QT; j++) {
        int m = m0 + j * TPB;
        const float* p = cloth + ((size_t)b * MM + m) * 3;
        float x = p[0], y = p[1], z = p[2];
        int pi = j >> 1;
        if (j & 1) { qx[pi].y = x; qy[pi].y = y; qz[pi].y = z;
                     bd[pi].y = __builtin_inff(); }
        else       { qx[pi].x = x; qy[pi].x = y; qz[pi].x = z;
                     bd[pi].x = __builtin_inff(); }
        tmin[j] = MIN_T2 - (x * x + y * y + z * z);  // e >= tmin <=> d2 >= MIN_T2
    }
    __syncthreads();

    // Hot loop: UNFILTERED min in shifted space e = s2 - 2 c.s
    // (3 pk_fma + 1 pk/2x min per float2-pair of queries; no index).
#pragma unroll 2
    for (int i = 0; i < segn; i++) {
        float4 c = lds[i];
        v2f cx = {c.x, c.x}, cy = {c.y, c.y}, cz = {c.z, c.z}, cw = {c.w, c.w};
#pragma unroll
        for (int p = 0; p < NPAIR; p++) {
            v2f e = __builtin_elementwise_fma(cx, qx[p],
                    __builtin_elementwise_fma(cy, qy[p],
                    __builtin_elementwise_fma(cz, qz[p], cw)));
            bd[p] = __builtin_elementwise_min(bd[p], e);
        }
    }

    float bds[QT];
#pragma unroll
    for (int p = 0; p < NPAIR; p++) { bds[2*p] = bd[p].x; bds[2*p+1] = bd[p].y; }

    // rare fallback: unfiltered min is a too-close candidate -> rescan this
    // segment with the full filter (if the min passes, all candidates do).
    // Invariant after this: bds[j] = min over {e : e >= tmin[j]} (or +inf).
#pragma unroll
    for (int j = 0; j < QT; j++) {
        if (bds[j] < tmin[j]) {
            float qxj = (j & 1) ? qx[j >> 1].y : qx[j >> 1].x;
            float qyj = (j & 1) ? qy[j >> 1].y : qy[j >> 1].x;
            float qzj = (j & 1) ? qz[j >> 1].y : qz[j >> 1].x;
            float fb = __builtin_inff();
            for (int i = 0; i < segn; i++) {
                float4 c = lds[i];
                float e = fmaf(c.x, qxj, fmaf(c.y, qyj, fmaf(c.z, qzj, c.w)));
                bool ok = (e >= tmin[j]) && (e < fb);
                fb = ok ? e : fb;
            }
            bds[j] = fb;
        }
    }

    // coalesced f32 partial store (shifted space; same shift -qc2 for all
    // segments of a query -> order across segments preserved).
#pragma unroll
    for (int j = 0; j < QT; j++) {
        int q = b * MM + m0 + j * TPB;
        partials[(size_t)seg * NQ + q] = bds[j];
    }
}

// Kernel 2: per-query scan of NSEG segment minima -> global min + FIRST
// segment achieving it (segments partition N in order, so first seg contains
// the lowest-index winner). Rescan that one segment (<=54 candidates) with
// the bit-identical fma chain to find the first index with e == vmin
// (fma is exactly rounded -> recompute matches phase 1 bit-for-bit).
// Then gather target, contribution, block-reduce; last block -> out[4].
__global__ __launch_bounds__(256) void finalize_kernel(
    const float* __restrict__ partials, const float* __restrict__ cloth,
    const float* __restrict__ vt, const int* __restrict__ valid,
    const int* __restrict__ smpl_idx, const float* __restrict__ sdf,
    const int* __restrict__ cloth_idx, const float* __restrict__ sdf_thresh,
    const float* __restrict__ dist_thresh,
    float* __restrict__ bsum, int* __restrict__ bmatch,
    unsigned int* __restrict__ counter, float* __restrict__ out)
{
    int q = blockIdx.x * 256 + threadIdx.x;   // 128 blocks x 256 = NQ
    int b = q >> 13;

    // first segment achieving the min (strict < keeps earliest)
    float vmin = __builtin_inff();
    int smin = 0;
#pragma unroll 4
    for (int s = 0; s < NSEG; s++) {
        float v = partials[(size_t)s * NQ + q];
        bool lt = v < vmin;
        vmin = lt ? v : vmin;
        smin = lt ? s : smin;
    }

    // query data
    const float* cp = cloth + (size_t)q * 3;
    float qx = cp[0], qy = cp[1], qz = cp[2];
    float qc2 = qx * qx + qy * qy + qz * qz;
    float tmin = MIN_T2 - qc2;

    // rescan winning segment for first index with e == vmin (and filtered).
    int n0 = smin * SEGN;
    int segn = (NN - n0 < SEGN) ? (NN - n0) : SEGN;
    int idx = 0;
    if (vmin < __builtin_inff()) {
        for (int i = 0; i < segn; i++) {
            const float* p = vt + ((size_t)b * NN + n0 + i) * 3;
            float x = p[0], y = p[1], z = p[2];
            float s2 = x * x + y * y + z * z;
            if (valid[b * NN + n0 + i] <= 0) s2 = __builtin_inff();
            float e = fmaf(-2.0f * x, qx,
                      fmaf(-2.0f * y, qy, fmaf(-2.0f * z, qz, s2)));
            if (e == vmin && e >= tmin) { idx = n0 + i; break; }
        }
    }

    float d2 = vmin + qc2;                        // +inf stays +inf
    int target = smpl_idx[b * NN + idx];
    int ci0 = cloth_idx[0], ci1 = cloth_idx[1];
    bool match = (target == ci0) || (target == ci1);
    bool near_ = sqrtf(d2) < dist_thresh[0];      // inf -> false
    float s = sdf[q];
    float contrib = near_ ? (match ? fabsf(s) : fabsf(s - sdf_thresh[0])) : 0.0f;
    int mt = match ? 1 : 0;

    for (int off = 32; off > 0; off >>= 1) {
        contrib += __shfl_down(contrib, off, 64);
        mt      |= __shfl_down(mt, off, 64);
    }
    __shared__ float wsum[4];
    __shared__ int   wmat[4];
    __shared__ int   isLast;
    int wave = threadIdx.x >> 6;
    if ((threadIdx.x & 63) == 0) { wsum[wave] = contrib; wmat[wave] = mt; }
    __syncthreads();
    if (threadIdx.x == 0) {
        bsum[blockIdx.x]   = wsum[0] + wsum[1] + wsum[2] + wsum[3];
        bmatch[blockIdx.x] = wmat[0] | wmat[1] | wmat[2] | wmat[3];
        __threadfence();                          // release block partials
        unsigned int old = atomicAdd(counter, 1); // device-scope
        isLast = (old == FBLK - 1) ? 1 : 0;
    }
    __syncthreads();

    if (isLast) {
        __threadfence();                          // acquire others' partials
        if (threadIdx.x < FBLK) {
            int t = threadIdx.x;                  // batch = t>>5, 32 per batch
            float sv = bsum[t];
            int   mv = bmatch[t];
            for (int off = 16; off > 0; off >>= 1) {
                sv += __shfl_down(sv, off, 32);   // 32-wide subgroups
                mv |= __shfl_down(mv, off, 32);
            }
            if ((t & 31) == 0)
                out[t >> 5] = sv * (1.0f / (float)MM) * (mv ? 1.0f : 0.0f);
        }
    }
}

extern "C" void kernel_launch(void* const* d_in, const int* in_sizes, int n_in,
                              void* d_out, int out_size, void* d_ws, size_t ws_size,
                              hipStream_t stream)
{
    const float* sdf         = (const float*)d_in[0];
    const float* cloth       = (const float*)d_in[1];
    const int*   smpl_idx    = (const int*)d_in[2];
    const int*   valid       = (const int*)d_in[3];
    const int*   cloth_idx   = (const int*)d_in[4];
    const float* sdf_thresh  = (const float*)d_in[5];
    const float* dist_thresh = (const float*)d_in[6];
    const float* vt          = (const float*)d_in[7];

    char* ws = (char*)d_ws;
    float*        partials = (float*)ws;
    float*        bsum     = (float*)(ws + OFF_BSUM);
    int*          bmatch   = (int*)(ws + OFF_BMATCH);
    unsigned int* counter  = (unsigned int*)(ws + OFF_CNT);

    nn_kernel<<<BB * CHUNKS * NSEG, TPB, 0, stream>>>(
        cloth, vt, valid, partials, counter);
    finalize_kernel<<<FBLK, 256, 0, stream>>>(
        partials, cloth, vt, valid, smpl_idx, sdf, cloth_idx,
        sdf_thresh, dist_thresh, bsum, bmatch, counter, (float*)d_out);
}